// Round 4
// baseline (34.484 us; speedup 1.0000x reference)
//
#include <hip/hip_runtime.h>

// Problem constants
#define NP     64      // params per cell
#define NC     2080    // NP*(NP+1)/2 packed upper-tri coefficients
#define NCELLS 4096    // 64*64 grid cells
#define NB     32      // batch
#define CELLS_PER_BLOCK 2          // 2 cells x 2 j-halves = 4 waves per block
#define BLOCKS (NCELLS / CELLS_PER_BLOCK)  // 2048

typedef short bf16x8 __attribute__((ext_vector_type(8)));   // 8 bf16 (4 VGPRs)
typedef float f32x16 __attribute__((ext_vector_type(16)));  // MFMA accumulator

// f32 -> bf16 bits, round-to-nearest-even.
__device__ __forceinline__ short f2bf(float f) {
  unsigned u = __float_as_uint(f);
  u += 0x7fffu + ((u >> 16) & 1u);
  return (short)(u >> 16);
}

// One wave per (cell, j-half). D = P(32b x 64i) * A(64i x 32j) with A the
// upper-tri matrix unpacked on the fly from packed triu coeffs; then
// out[b] += sum_j D[b,j] * P[b,j]. Deterministic 2-stage reduction via ws.
__global__ __launch_bounds__(256, 6) void poly_mfma_kernel(
    const float* __restrict__ param,   // [NB][NCELLS][NP]
    const float* __restrict__ coeffs,  // [NCELLS][NC]
    float* __restrict__ ws) {          // [NB][BLOCKS] (transposed!)
  const int tid  = threadIdx.x;
  const int wave = tid >> 6;       // 0..3
  const int lane = tid & 63;
  const int lo5  = lane & 31;      // A-row b; B/C column j (within half)
  const int hi   = lane >> 5;
  const int cl   = wave >> 1;      // cell within block
  const int jh   = wave & 1;       // j-half: columns [32*jh, 32*jh+32)
  const int cell = blockIdx.x * CELLS_PER_BLOCK + cl;
  const int jg   = 32 * jh + lo5;  // global column j

  // ---- A-operand fragments: P rows. row b = lo5,
  //      k_i = ks*16 + 4*hi + (e&3) + 8*(e>>2)  (same k-map used for B).
  const float* pb = param + ((size_t)lo5 * NCELLS + cell) * NP;
  bf16x8 afrag[4];
#pragma unroll
  for (int ks = 0; ks < 4; ++ks) {
#pragma unroll
    for (int eh = 0; eh < 2; ++eh) {
      const int i0 = ks * 16 + 4 * hi + 8 * eh;
      const float4 v = *reinterpret_cast<const float4*>(pb + i0);
      afrag[ks][eh * 4 + 0] = f2bf(v.x);
      afrag[ks][eh * 4 + 1] = f2bf(v.y);
      afrag[ks][eh * 4 + 2] = f2bf(v.z);
      afrag[ks][eh * 4 + 3] = f2bf(v.w);
    }
  }

  // ---- B-operand gathers (upper-tri A_cell from packed coeffs) + MFMAs.
  // c(i,j) = i*(127-i)/2 + j for i<=j (addresses valid for all j in [0,64)).
  const float* cb = coeffs + (size_t)cell * NC;
  f32x16 acc;
#pragma unroll
  for (int r = 0; r < 16; ++r) acc[r] = 0.f;

#pragma unroll
  for (int ks = 0; ks < 4; ++ks) {
    bf16x8 bfr;
#pragma unroll
    for (int e = 0; e < 8; ++e) {
      const int i = ks * 16 + 4 * hi + (e & 3) + 8 * (e >> 2);
      const int cbase = i * (127 - i) / 2;
      const float v = (jg >= i) ? cb[cbase + jg] : 0.f;
      bfr[e] = f2bf(v);
    }
    acc = __builtin_amdgcn_mfma_f32_32x32x16_bf16(afrag[ks], bfr, acc, 0, 0, 0);
  }

  // ---- Epilogue: multiply by P[b, jg] and reduce over j within the half.
  // C/D layout (HW-verified): col = lane&31, row b = (r&3)+8*(r>>2)+4*hi.
  __shared__ float sred[4][NB];
  float dacc[16];
#pragma unroll
  for (int r = 0; r < 16; ++r) {
    const int b = (r & 3) + 8 * (r >> 2) + 4 * hi;
    const float* pe = param + ((size_t)b * NCELLS + cell) * NP;
    dacc[r] = acc[r] * pe[jg];
  }
#pragma unroll
  for (int r = 0; r < 16; ++r) {
    float v = dacc[r];
    v += __shfl_xor(v, 1, 64);
    v += __shfl_xor(v, 2, 64);
    v += __shfl_xor(v, 4, 64);
    v += __shfl_xor(v, 8, 64);
    v += __shfl_xor(v, 16, 64);
    dacc[r] = v;
  }
  if (lo5 == 0) {  // lanes 0 / 32 hold disjoint b-sets (offset 0 / 4)
#pragma unroll
    for (int r = 0; r < 16; ++r) {
      const int b = (r & 3) + 8 * (r >> 2) + 4 * hi;
      sred[wave][b] = dacc[r];
    }
  }
  __syncthreads();
  if (tid < NB) {
    // 4 waves = 2 cells x 2 j-halves; sum them all.
    ws[(size_t)tid * BLOCKS + blockIdx.x] =
        sred[0][tid] + sred[1][tid] + sred[2][tid] + sred[3][tid];
  }
}

// Sum ws[NB][BLOCKS] over blocks -> out[NB]. Single block, deterministic.
// Thread (b = tid>>3, part = tid&7) reduces a contiguous 256-float4 run.
__global__ void poly_reduce_kernel(const float* __restrict__ ws,
                                   float* __restrict__ out) {
  __shared__ float sred[NB][8];
  const int tid = threadIdx.x;
  const int b = tid >> 3;
  const int part = tid & 7;
  const float4* src =
      reinterpret_cast<const float4*>(ws + (size_t)b * BLOCKS + part * (BLOCKS / 8));
  float s = 0.f;
#pragma unroll 4
  for (int k = 0; k < BLOCKS / 8 / 4; ++k) {
    float4 v = src[k];
    s += (v.x + v.y) + (v.z + v.w);
  }
  sred[b][part] = s;
  __syncthreads();
  if (tid < NB) {
    float t = 0.f;
#pragma unroll
    for (int q = 0; q < 8; ++q) t += sred[tid][q];
    out[tid] = t;
  }
}

extern "C" void kernel_launch(void* const* d_in, const int* in_sizes, int n_in,
                              void* d_out, int out_size, void* d_ws,
                              size_t ws_size, hipStream_t stream) {
  const float* param = (const float*)d_in[0];   // [32,64,64,64] f32
  const float* coeffs = (const float*)d_in[1];  // [64,64,2080] f32
  float* out = (float*)d_out;                   // [32] f32
  float* ws = (float*)d_ws;                     // NB*BLOCKS*4 = 256 KB

  hipLaunchKernelGGL(poly_mfma_kernel, dim3(BLOCKS), dim3(256), 0, stream,
                     param, coeffs, ws);
  hipLaunchKernelGGL(poly_reduce_kernel, dim3(1), dim3(256), 0, stream, ws,
                     out);
}

// Round 5
// 24.263 us; speedup vs baseline: 1.4212x; 1.4212x over previous
//
#include <hip/hip_runtime.h>

// Problem constants
#define NP     64      // params per cell
#define NC     2080    // NP*(NP+1)/2 packed upper-tri coefficients
#define NCELLS 4096    // 64*64 grid cells
#define NB     32      // batch
#define CELLS_PER_BLOCK 4                   // one cell per wave
#define BLOCKS (NCELLS / CELLS_PER_BLOCK)   // 1024

typedef short bf16x8 __attribute__((ext_vector_type(8)));   // 8 bf16 (4 VGPRs)
typedef float f32x16 __attribute__((ext_vector_type(16)));  // MFMA accumulator

// f32 -> bf16 bits, round-to-nearest-even.
__device__ __forceinline__ short f2bf(float f) {
  unsigned u = __float_as_uint(f);
  u += 0x7fffu + ((u >> 16) & 1u);
  return (short)(u >> 16);
}

// One wave per cell. Coeffs staged wave-privately into LDS via coalesced
// float4 streams (prefetch-friendly for cold HBM); the 64 triangular B-operand
// gathers become cheap ds_read_b32. D = P(32b x 64i) * A(64i x 64j) upper-tri,
// then out[b] += sum_j D[b,j] * P[b,j]. Deterministic reduction via ws.
__global__ __launch_bounds__(256, 4) void poly_mfma_kernel(
    const float* __restrict__ param,   // [NB][NCELLS][NP]
    const float* __restrict__ coeffs,  // [NCELLS][NC]
    float* __restrict__ ws) {          // [BLOCKS][NB]
  __shared__ float scoef[CELLS_PER_BLOCK][NC];  // 33.3 KB
  __shared__ float sred[CELLS_PER_BLOCK][NB];

  const int tid  = threadIdx.x;
  const int wave = tid >> 6;
  const int lane = tid & 63;
  const int lo5  = lane & 31;  // A-row b; B/C column j (within half)
  const int hi   = lane >> 5;
  const int cell = blockIdx.x * CELLS_PER_BLOCK + wave;

  // ---- Wave-private coeff staging: 2080 floats = 520 float4.
  // 8 full 64-lane rounds + an 8-lane tail. No __syncthreads needed: this
  // wave is the only reader. Sequential 8.3 KB stream -> HW prefetch.
  {
    const float4* gsrc =
        reinterpret_cast<const float4*>(coeffs + (size_t)cell * NC);
    float4* ldst = reinterpret_cast<float4*>(&scoef[wave][0]);
#pragma unroll
    for (int k = 0; k < 8; ++k) ldst[k * 64 + lane] = gsrc[k * 64 + lane];
    if (lane < 8) ldst[512 + lane] = gsrc[512 + lane];
  }

  // ---- A-operand fragments: P rows. row b = lo5,
  //      k_i = ks*16 + 4*hi + (e&3) + 8*(e>>2)  (same k-map used for B:
  //      any consistent k-slot permutation cancels between A and B).
  const float* pb = param + ((size_t)lo5 * NCELLS + cell) * NP;
  bf16x8 afrag[4];
#pragma unroll
  for (int ks = 0; ks < 4; ++ks) {
#pragma unroll
    for (int eh = 0; eh < 2; ++eh) {
      const int i0 = ks * 16 + 4 * hi + 8 * eh;
      const float4 v = *reinterpret_cast<const float4*>(pb + i0);
      afrag[ks][eh * 4 + 0] = f2bf(v.x);
      afrag[ks][eh * 4 + 1] = f2bf(v.y);
      afrag[ks][eh * 4 + 2] = f2bf(v.z);
      afrag[ks][eh * 4 + 3] = f2bf(v.w);
    }
  }

  // ---- B-operand gathers from LDS (upper-tri unpack) + MFMAs.
  // c(i,j) = i*(127-i)/2 + j for i<=j; below-diagonal forced to zero.
  const float* sw = &scoef[wave][0];
  f32x16 acc0, acc1;  // j in [0,32) and [32,64)
#pragma unroll
  for (int r = 0; r < 16; ++r) { acc0[r] = 0.f; acc1[r] = 0.f; }

#pragma unroll
  for (int ks = 0; ks < 4; ++ks) {
    bf16x8 b0, b1;
#pragma unroll
    for (int e = 0; e < 8; ++e) {
      const int i = ks * 16 + 4 * hi + (e & 3) + 8 * (e >> 2);
      const int cbase = i * (127 - i) / 2;
      const float v0 = (lo5 >= i) ? sw[cbase + lo5] : 0.f;
      const float v1 = (lo5 + 32 >= i) ? sw[cbase + lo5 + 32] : 0.f;
      b0[e] = f2bf(v0);
      b1[e] = f2bf(v1);
    }
    acc0 = __builtin_amdgcn_mfma_f32_32x32x16_bf16(afrag[ks], b0, acc0, 0, 0, 0);
    acc1 = __builtin_amdgcn_mfma_f32_32x32x16_bf16(afrag[ks], b1, acc1, 0, 0, 0);
  }

  // ---- Epilogue: dacc[r] = sum over this lane's j of D[b,j]*P[b,j].
  // C/D layout (HW-verified): col = lane&31, row b = (r&3)+8*(r>>2)+4*hi.
  // pe reads hit L1: this wave's A-frag loads already touched these lines.
  float dacc[16];
#pragma unroll
  for (int r = 0; r < 16; ++r) {
    const int b = (r & 3) + 8 * (r >> 2) + 4 * hi;
    const float* pe = param + ((size_t)b * NCELLS + cell) * NP;
    dacc[r] = fmaf(acc0[r], pe[lo5], acc1[r] * pe[lo5 + 32]);
  }

  // ---- Reduce over j (lo5) within each 32-lane half.
#pragma unroll
  for (int r = 0; r < 16; ++r) {
    float v = dacc[r];
    v += __shfl_xor(v, 1, 64);
    v += __shfl_xor(v, 2, 64);
    v += __shfl_xor(v, 4, 64);
    v += __shfl_xor(v, 8, 64);
    v += __shfl_xor(v, 16, 64);
    dacc[r] = v;
  }
  if (lo5 == 0) {  // lanes 0 / 32 hold disjoint b-sets (offset 0 / 4)
#pragma unroll
    for (int r = 0; r < 16; ++r) {
      const int b = (r & 3) + 8 * (r >> 2) + 4 * hi;
      sred[wave][b] = dacc[r];
    }
  }
  __syncthreads();
  if (tid < NB) {
    ws[(size_t)blockIdx.x * NB + tid] =
        sred[0][tid] + sred[1][tid] + sred[2][tid] + sred[3][tid];
  }
}

// Sum ws[BLOCKS][NB] over blocks -> out[NB]. Single block, deterministic.
__global__ void poly_reduce_kernel(const float* __restrict__ ws,
                                   float* __restrict__ out) {
  __shared__ float sred[8][NB];
  const int tid = threadIdx.x;
  const int b = tid & 31;
  const int part = tid >> 5;  // 0..7
  float s = 0.f;
  for (int k = 0; k < BLOCKS / 8; ++k) {
    s += ws[(size_t)(part * (BLOCKS / 8) + k) * NB + b];
  }
  sred[part][b] = s;
  __syncthreads();
  if (tid < NB) {
    float t = 0.f;
#pragma unroll
    for (int q = 0; q < 8; ++q) t += sred[q][tid];
    out[tid] = t;
  }
}

extern "C" void kernel_launch(void* const* d_in, const int* in_sizes, int n_in,
                              void* d_out, int out_size, void* d_ws,
                              size_t ws_size, hipStream_t stream) {
  const float* param = (const float*)d_in[0];   // [32,64,64,64] f32
  const float* coeffs = (const float*)d_in[1];  // [64,64,2080] f32
  float* out = (float*)d_out;                   // [32] f32
  float* ws = (float*)d_ws;                     // BLOCKS*NB*4 = 128 KB

  hipLaunchKernelGGL(poly_mfma_kernel, dim3(BLOCKS), dim3(256), 0, stream,
                     param, coeffs, ws);
  hipLaunchKernelGGL(poly_reduce_kernel, dim3(1), dim3(256), 0, stream, ws,
                     out);
}

// Round 6
// 22.300 us; speedup vs baseline: 1.5464x; 1.0881x over previous
//
#include <hip/hip_runtime.h>

// Problem constants
#define NP     64      // params per cell
#define NC     2080    // NP*(NP+1)/2 packed upper-tri coefficients
#define NCELLS 4096    // 64*64 grid cells
#define NB     32      // batch
#define CELLS_PER_BLOCK 4                   // one cell per wave
#define BLOCKS (NCELLS / CELLS_PER_BLOCK)   // 1024
#define CSTRIDE 2112   // bf16 shorts per cell in LDS (2080 padded, 8B-aligned)

typedef short bf16x8  __attribute__((ext_vector_type(8)));  // MFMA A/B frag
typedef short short4v __attribute__((ext_vector_type(4)));
typedef float f32x16  __attribute__((ext_vector_type(16))); // MFMA accumulator

// f32 -> bf16 bits, round-to-nearest-even.
__device__ __forceinline__ short f2bf(float f) {
  unsigned u = __float_as_uint(f);
  u += 0x7fffu + ((u >> 16) & 1u);
  return (short)(u >> 16);
}

// One wave per cell. Coeffs block-coop staged as PACKED-TRIU bf16 in LDS
// (converted during staging -> no f2bf in the inner loop). Epilogue P-values
// are loaded EARLY (issue-before-MFMA, consume-after: T14) so their global
// latency hides under the ds_read+MFMA phase.
__global__ __launch_bounds__(256, 4) void poly_mfma_kernel(
    const float* __restrict__ param,   // [NB][NCELLS][NP]
    const float* __restrict__ coeffs,  // [NCELLS][NC]
    float* __restrict__ ws) {          // [NB][BLOCKS] (transposed)
  __shared__ short scoefh[CELLS_PER_BLOCK][CSTRIDE];  // 16.5 KB
  __shared__ float sred[CELLS_PER_BLOCK][NB];

  const int tid  = threadIdx.x;
  const int wave = tid >> 6;
  const int lane = tid & 63;
  const int lo5  = lane & 31;  // A-row b; B/C column j (within half)
  const int hi   = lane >> 5;
  const int cellbase = blockIdx.x * CELLS_PER_BLOCK;
  const int cell = cellbase + wave;

  // ---- Block-coop staging: 4 cells x 2080 f32 -> packed bf16 LDS.
  // 2080 float4 total; 520 per cell (divisible: no group straddles a cell).
  {
    const float4* gsrc =
        reinterpret_cast<const float4*>(coeffs + (size_t)cellbase * NC);
#pragma unroll
    for (int k = 0; k < 9; ++k) {
      const int idx = tid + k * 256;
      if (idx < (CELLS_PER_BLOCK * NC) / 4) {
        const int cl = idx / 520;
        const int q  = idx - cl * 520;
        const float4 v = gsrc[idx];
        short4v h;
        h[0] = f2bf(v.x); h[1] = f2bf(v.y);
        h[2] = f2bf(v.z); h[3] = f2bf(v.w);
        *reinterpret_cast<short4v*>(&scoefh[cl][4 * q]) = h;
      }
    }
  }

  // ---- A-operand fragments (global, independent of staging -> overlaps).
  // row b = lo5, k_i = ks*16 + 4*hi + (e&3) + 8*(e>>2) (same k-map as B:
  // a consistent A/B k-slot permutation cancels in hardware).
  const float* pb = param + ((size_t)lo5 * NCELLS + cell) * NP;
  bf16x8 afrag[4];
#pragma unroll
  for (int ks = 0; ks < 4; ++ks) {
#pragma unroll
    for (int eh = 0; eh < 2; ++eh) {
      const int i0 = ks * 16 + 4 * hi + 8 * eh;
      const float4 v = *reinterpret_cast<const float4*>(pb + i0);
      afrag[ks][eh * 4 + 0] = f2bf(v.x);
      afrag[ks][eh * 4 + 1] = f2bf(v.y);
      afrag[ks][eh * 4 + 2] = f2bf(v.z);
      afrag[ks][eh * 4 + 3] = f2bf(v.w);
    }
  }

  __syncthreads();

  // ---- T14: issue epilogue P-loads NOW, consume after the MFMA section.
  // C/D layout (HW-verified): col j = lane&31, row b = (r&3)+8*(r>>2)+4*hi.
  float pepi0[16], pepi1[16];
#pragma unroll
  for (int r = 0; r < 16; ++r) {
    const int b = (r & 3) + 8 * (r >> 2) + 4 * hi;
    const float* pe = param + ((size_t)b * NCELLS + cell) * NP;
    pepi0[r] = pe[lo5];
    pepi1[r] = pe[lo5 + 32];
  }

  // ---- B-operand gathers from bf16 LDS (upper-tri unpack) + MFMAs.
  // c(i,j) = i*(127-i)/2 + j for i<=j; below-diagonal zeroed via cndmask.
  const short* sw = &scoefh[wave][0];
  f32x16 acc0, acc1;  // j in [0,32) and [32,64)
#pragma unroll
  for (int r = 0; r < 16; ++r) { acc0[r] = 0.f; acc1[r] = 0.f; }

#pragma unroll
  for (int ks = 0; ks < 4; ++ks) {
    bf16x8 b0, b1;
#pragma unroll
    for (int e = 0; e < 8; ++e) {
      const int i = ks * 16 + 4 * hi + (e & 3) + 8 * (e >> 2);
      const int cbase = i * (127 - i) / 2;  // compile-time per e
      const short v0 = sw[cbase + lo5];
      const short v1 = sw[cbase + lo5 + 32];
      b0[e] = (lo5 >= i) ? v0 : (short)0;
      b1[e] = (lo5 + 32 >= i) ? v1 : (short)0;
    }
    acc0 = __builtin_amdgcn_mfma_f32_32x32x16_bf16(afrag[ks], b0, acc0, 0, 0, 0);
    acc1 = __builtin_amdgcn_mfma_f32_32x32x16_bf16(afrag[ks], b1, acc1, 0, 0, 0);
  }

  // ---- Epilogue: dacc[r] = D[b, jg]*P[b, jg] (+ the j+32 half).
  float dacc[16];
#pragma unroll
  for (int r = 0; r < 16; ++r)
    dacc[r] = fmaf(acc0[r], pepi0[r], acc1[r] * pepi1[r]);

  // ---- Reduce over j (lo5) within each 32-lane half.
#pragma unroll
  for (int r = 0; r < 16; ++r) {
    float v = dacc[r];
    v += __shfl_xor(v, 1, 64);
    v += __shfl_xor(v, 2, 64);
    v += __shfl_xor(v, 4, 64);
    v += __shfl_xor(v, 8, 64);
    v += __shfl_xor(v, 16, 64);
    dacc[r] = v;
  }
  if (lo5 == 0) {  // lanes 0 / 32 hold disjoint b-sets (offset 0 / 4)
#pragma unroll
    for (int r = 0; r < 16; ++r) {
      const int b = (r & 3) + 8 * (r >> 2) + 4 * hi;
      sred[wave][b] = dacc[r];
    }
  }
  __syncthreads();
  if (tid < NB) {
    ws[(size_t)tid * BLOCKS + blockIdx.x] =
        sred[0][tid] + sred[1][tid] + sred[2][tid] + sred[3][tid];
  }
}

// One block per b: sum ws[b][0..BLOCKS) -> out[b]. 256 threads x 1 float4.
__global__ void poly_reduce_kernel(const float* __restrict__ ws,
                                   float* __restrict__ out) {
  const int b = blockIdx.x;
  const int tid = threadIdx.x;
  const float4 v =
      reinterpret_cast<const float4*>(ws + (size_t)b * BLOCKS)[tid];
  float s = (v.x + v.y) + (v.z + v.w);
#pragma unroll
  for (int off = 1; off <= 32; off <<= 1) s += __shfl_xor(s, off, 64);
  __shared__ float sp[4];
  if ((tid & 63) == 0) sp[tid >> 6] = s;
  __syncthreads();
  if (tid == 0) out[b] = (sp[0] + sp[1]) + (sp[2] + sp[3]);
}

extern "C" void kernel_launch(void* const* d_in, const int* in_sizes, int n_in,
                              void* d_out, int out_size, void* d_ws,
                              size_t ws_size, hipStream_t stream) {
  const float* param = (const float*)d_in[0];   // [32,64,64,64] f32
  const float* coeffs = (const float*)d_in[1];  // [64,64,2080] f32
  float* out = (float*)d_out;                   // [32] f32
  float* ws = (float*)d_ws;                     // NB*BLOCKS*4 = 128 KB

  hipLaunchKernelGGL(poly_mfma_kernel, dim3(BLOCKS), dim3(256), 0, stream,
                     param, coeffs, ws);
  hipLaunchKernelGGL(poly_reduce_kernel, dim3(NB), dim3(256), 0, stream, ws,
                     out);
}

// Round 8
// 21.672 us; speedup vs baseline: 1.5912x; 1.0290x over previous
//
#include <hip/hip_runtime.h>

// Problem constants
#define NP     64      // params per cell
#define NC     2080    // NP*(NP+1)/2 packed upper-tri coefficients
#define NCELLS 4096    // 64*64 grid cells
#define NB     32      // batch
#define CELLS_PER_BLOCK 4                   // one cell per wave
#define BLOCKS (NCELLS / CELLS_PER_BLOCK)   // 1024

typedef short bf16x8  __attribute__((ext_vector_type(8)));  // MFMA A/B frag
typedef short short4v __attribute__((ext_vector_type(4)));  // one ds_read_b64
typedef float f32x16  __attribute__((ext_vector_type(16))); // MFMA accumulator

// f32 -> bf16 bits, round-to-nearest-even.
__device__ __forceinline__ short f2bf(float f) {
  unsigned u = __float_as_uint(f);
  u += 0x7fffu + ((u >> 16) & 1u);
  return (short)(u >> 16);
}

// Swizzled physical i-index for A_T[j][i]: XOR bits[5:2] with j&15.
// Bits >=2 only => 4-aligned groups of 4 stay contiguous (ds_read_b64-able)
// and the A/B k-slot pairing is unchanged.
__device__ __forceinline__ int swz(int j, int i) { return i ^ ((j & 15) << 2); }

// DPP row_ror sum; ctrl must be an ICE -> template parameter.
template <int CTRL>
__device__ __forceinline__ float ror_add(float v) {
  int t = __builtin_amdgcn_update_dpp(0, __float_as_int(v), CTRL, 0xf, 0xf, true);
  return v + __int_as_float(t);
}

// One wave per cell. The packed-triu coeff row is unpacked ON STAGE into a
// zero-filled transposed bf16 tile A_T[j][i] in LDS (wave-private, no
// barrier), so the MFMA B-operand is 16 ds_read_b64 instead of 128
// ds_read_u16. Epilogue P loaded early (T14); j-reduction via DPP row_ror
// (VALU) + one ds_swizzle xor16.
__global__ __launch_bounds__(256, 4) void poly_mfma_kernel(
    const float* __restrict__ param,   // [NB][NCELLS][NP]
    const float* __restrict__ coeffs,  // [NCELLS][NC]
    float* __restrict__ ws) {          // [NB][BLOCKS] (transposed)
  __shared__ __align__(16) short scoefT[CELLS_PER_BLOCK][NP][NP];  // 32 KB
  __shared__ float sred[CELLS_PER_BLOCK][NB];

  const int tid  = threadIdx.x;
  const int wave = tid >> 6;
  const int lane = tid & 63;
  const int lo5  = lane & 31;  // A-row b; B/C column j (within half)
  const int hi   = lane >> 5;
  const int cell = blockIdx.x * CELLS_PER_BLOCK + wave;

  // ---- Zero-fill this wave's A_T tile (below-diagonal stays 0).
  {
    int4* z = reinterpret_cast<int4*>(&scoefT[wave][0][0]);
    const int4 zero = {0, 0, 0, 0};
#pragma unroll
    for (int k = 0; k < 8; ++k) z[k * 64 + lane] = zero;
  }

  // ---- Wave-private staging: packed triu f32 -> unpacked transposed bf16.
  // Linear index c -> (i,j): i from the exact identity
  // 16641 - 8*base_i = (129-2i)^2  (f32 sqrt exact at row boundaries).
  {
    const float4* gsrc =
        reinterpret_cast<const float4*>(coeffs + (size_t)cell * NC);
#pragma unroll
    for (int k = 0; k < 9; ++k) {
      const int idx = k * 64 + lane;
      if (idx < NC / 4) {
        const float4 v = gsrc[idx];
        const int c = idx * 4;
        const float fs = sqrtf((float)(16641 - 8 * c));
        int i = (int)((129.0f - fs) * 0.5f);
        int bi = 64 * i - ((i * (i - 1)) >> 1);
        if (c < bi) { --i; bi -= (64 - i); }
        else if (c >= bi + (64 - i)) { bi += (64 - i); ++i; }
        int off = c - bi;  // offset within row i
        const float vals[4] = {v.x, v.y, v.z, v.w};
#pragma unroll
        for (int d = 0; d < 4; ++d) {
          const int j = i + off;
          scoefT[wave][j][swz(j, i)] = f2bf(vals[d]);
          ++off;
          if (off == 64 - i) { ++i; off = 0; }
        }
      }
    }
  }

  // ---- A-operand fragments (global). row b = lo5,
  //      k_i = ks*16 + 4*hi + (e&3) + 8*(e>>2) (same k-map as B).
  const float* pb = param + ((size_t)lo5 * NCELLS + cell) * NP;
  bf16x8 afrag[4];
#pragma unroll
  for (int ks = 0; ks < 4; ++ks) {
#pragma unroll
    for (int eh = 0; eh < 2; ++eh) {
      const int i0 = ks * 16 + 4 * hi + 8 * eh;
      const float4 v = *reinterpret_cast<const float4*>(pb + i0);
      afrag[ks][eh * 4 + 0] = f2bf(v.x);
      afrag[ks][eh * 4 + 1] = f2bf(v.y);
      afrag[ks][eh * 4 + 2] = f2bf(v.z);
      afrag[ks][eh * 4 + 3] = f2bf(v.w);
    }
  }

  // ---- T14: issue epilogue P-loads now, consume after MFMAs.
  // C/D layout (HW-verified): col j = lane&31, row b = (r&3)+8*(r>>2)+4*hi.
  float pepi0[16], pepi1[16];
#pragma unroll
  for (int r = 0; r < 16; ++r) {
    const int b = (r & 3) + 8 * (r >> 2) + 4 * hi;
    const float* pe = param + ((size_t)b * NCELLS + cell) * NP;
    pepi0[r] = pe[lo5];
    pepi1[r] = pe[lo5 + 32];
  }

  // ---- B-operand: 16x ds_read_b64 from the transposed tile + 8 MFMAs.
  const short* swT = &scoefT[wave][0][0];
  const int jb0 = lo5 * NP;         // j = lo5
  const int jb1 = (lo5 + 32) * NP;  // j = lo5+32 (same swizzle: j&15 equal)
  f32x16 acc0, acc1;
#pragma unroll
  for (int r = 0; r < 16; ++r) { acc0[r] = 0.f; acc1[r] = 0.f; }

#pragma unroll
  for (int ks = 0; ks < 4; ++ks) {
    const int ia = ks * 16 + 4 * hi;      // eh=0 group base
    const int ib = ia + 8;                // eh=1 group base
    const short4v a0 = *reinterpret_cast<const short4v*>(swT + jb0 + swz(lo5, ia));
    const short4v a1 = *reinterpret_cast<const short4v*>(swT + jb0 + swz(lo5, ib));
    const short4v c0 = *reinterpret_cast<const short4v*>(swT + jb1 + swz(lo5, ia));
    const short4v c1 = *reinterpret_cast<const short4v*>(swT + jb1 + swz(lo5, ib));
    const bf16x8 b0 = __builtin_shufflevector(a0, a1, 0, 1, 2, 3, 4, 5, 6, 7);
    const bf16x8 b1 = __builtin_shufflevector(c0, c1, 0, 1, 2, 3, 4, 5, 6, 7);
    acc0 = __builtin_amdgcn_mfma_f32_32x32x16_bf16(afrag[ks], b0, acc0, 0, 0, 0);
    acc1 = __builtin_amdgcn_mfma_f32_32x32x16_bf16(afrag[ks], b1, acc1, 0, 0, 0);
  }

  // ---- Epilogue: dacc = D[b,j]*P[b,j] + D[b,j+32]*P[b,j+32]; reduce over j.
#pragma unroll
  for (int r = 0; r < 16; ++r) {
    float v = fmaf(acc0[r], pepi0[r], acc1[r] * pepi1[r]);
    // 16-lane row sum on the VALU pipe (DPP row_ror 1,2,4,8)...
    v = ror_add<0x121>(v);
    v = ror_add<0x122>(v);
    v = ror_add<0x124>(v);
    v = ror_add<0x128>(v);
    // ...then one cross-row xor16 swizzle completes the 32-lane half-sum.
    v += __int_as_float(__builtin_amdgcn_ds_swizzle(__float_as_int(v), 0x401F));
    if (lo5 == 0) {
      const int b = (r & 3) + 8 * (r >> 2) + 4 * hi;
      sred[wave][b] = v;
    }
  }
  __syncthreads();
  if (tid < NB) {
    ws[(size_t)tid * BLOCKS + blockIdx.x] =
        sred[0][tid] + sred[1][tid] + sred[2][tid] + sred[3][tid];
  }
}

// One block per b: sum ws[b][0..BLOCKS) -> out[b]. 256 threads x 1 float4.
__global__ void poly_reduce_kernel(const float* __restrict__ ws,
                                   float* __restrict__ out) {
  const int b = blockIdx.x;
  const int tid = threadIdx.x;
  const float4 v =
      reinterpret_cast<const float4*>(ws + (size_t)b * BLOCKS)[tid];
  float s = (v.x + v.y) + (v.z + v.w);
#pragma unroll
  for (int off = 1; off <= 32; off <<= 1) s += __shfl_xor(s, off, 64);
  __shared__ float sp[4];
  if ((tid & 63) == 0) sp[tid >> 6] = s;
  __syncthreads();
  if (tid == 0) out[b] = (sp[0] + sp[1]) + (sp[2] + sp[3]);
}

extern "C" void kernel_launch(void* const* d_in, const int* in_sizes, int n_in,
                              void* d_out, int out_size, void* d_ws,
                              size_t ws_size, hipStream_t stream) {
  const float* param = (const float*)d_in[0];   // [32,64,64,64] f32
  const float* coeffs = (const float*)d_in[1];  // [64,64,2080] f32
  float* out = (float*)d_out;                   // [32] f32
  float* ws = (float*)d_ws;                     // NB*BLOCKS*4 = 128 KB

  hipLaunchKernelGGL(poly_mfma_kernel, dim3(BLOCKS), dim3(256), 0, stream,
                     param, coeffs, ws);
  hipLaunchKernelGGL(poly_reduce_kernel, dim3(NB), dim3(256), 0, stream, ws,
                     out);
}